// Round 1
// baseline (38.044 us; speedup 1.0000x reference)
//
#include <hip/hip_runtime.h>
#include <math.h>

#define BB 128
#define CC 1024
#define BLOCK 256

// Per-batch kernel: exploits sparsity of y. Writes partial sum per batch into ws.
__global__ __launch_bounds__(BLOCK) void asl_partial_kernel(
    const float* __restrict__ x, const float* __restrict__ y,
    const float* __restrict__ mask, float* __restrict__ partial) {
  const int b = blockIdx.x;
  const int tid = threadIdx.x;

  __shared__ int   jidx[CC];   // compacted nonzero-y column indices
  __shared__ float jw[CC];     // corresponding w = x^2 (y==1 so x^2*y = x^2)
  __shared__ int   nnz;
  __shared__ float red[BLOCK / 64];

  if (tid == 0) nnz = 0;
  __syncthreads();

  const float* xb = x + (size_t)b * CC;
  const float* yb = y + (size_t)b * CC;

  // Compact the nonzero-y entries (order irrelevant: max is order-independent).
  for (int j = tid; j < CC; j += BLOCK) {
    float yv = yb[j];
    if (yv != 0.0f) {
      float xv = xb[j];
      int p = atomicAdd(&nnz, 1);
      jidx[p] = j;
      jw[p]   = xv * xv;
    }
  }
  __syncthreads();
  const int n = nnz;

  float acc = 0.0f;
  for (int i = tid; i < CC; i += BLOCK) {
    float xv = xb[i];
    float yv = yb[i];
    float term;
    if (yv != 0.0f) {
      // xp = mm = max_j mask[i,j] * x[b,j]^2 * y[b,j]; diagonal ensures mm >= xv^2 > 0
      const float* mrow = mask + (size_t)i * CC;
      float mm = 0.0f;
      for (int k = 0; k < n; ++k) {
        float m = mrow[jidx[k]];        // 0.0 or 1.0
        mm = fmaxf(mm, m * jw[k]);
      }
      // loss_pos = log(mm)  (GAMMA_POS = 0 -> pow term is 1)
      term = logf(mm);
    } else {
      // xp = x; loss_neg = xp^4 * log(1 - xp)
      float x2 = xv * xv;
      term = (x2 * x2) * logf(1.0f - xv);
    }
    acc += term;
  }

  // Block reduction: wave shuffle then cross-wave via LDS.
  for (int off = 32; off > 0; off >>= 1)
    acc += __shfl_down(acc, off, 64);
  const int lane = tid & 63, wid = tid >> 6;
  if (lane == 0) red[wid] = acc;
  __syncthreads();
  if (tid == 0) {
    float s = 0.0f;
    #pragma unroll
    for (int w = 0; w < BLOCK / 64; ++w) s += red[w];
    partial[b] = s;
  }
}

// Final reduction of 128 partials -> scalar mean with negation.
__global__ __launch_bounds__(128) void asl_final_kernel(
    const float* __restrict__ partial, float* __restrict__ out) {
  const int tid = threadIdx.x;  // 128 threads
  float v = partial[tid];
  for (int off = 32; off > 0; off >>= 1)
    v += __shfl_down(v, off, 64);
  __shared__ float s2[2];
  if ((tid & 63) == 0) s2[tid >> 6] = v;
  __syncthreads();
  if (tid == 0) out[0] = -(s2[0] + s2[1]) * (1.0f / (float)(BB * CC));
}

extern "C" void kernel_launch(void* const* d_in, const int* in_sizes, int n_in,
                              void* d_out, int out_size, void* d_ws, size_t ws_size,
                              hipStream_t stream) {
  const float* x    = (const float*)d_in[0];
  const float* y    = (const float*)d_in[1];
  const float* mask = (const float*)d_in[2];
  float* out = (float*)d_out;
  float* partial = (float*)d_ws;  // 128 floats; fully rewritten each call

  asl_partial_kernel<<<BB, BLOCK, 0, stream>>>(x, y, mask, partial);
  asl_final_kernel<<<1, 128, 0, stream>>>(partial, out);
}

// Round 2
// 14.523 us; speedup vs baseline: 2.6195x; 2.6195x over previous
//
#include <hip/hip_runtime.h>
#include <math.h>

#define BB 128
#define CC 1024
#define SPLIT 8                 // blocks per batch
#define CHUNK (CC / SPLIT)      // 128 i's per block
#define BLOCK 256
#define NW (BLOCK / 64)         // waves per block
#define NBLK (BB * SPLIT)

// One block handles batch b, i-range [i0, i0+CHUNK).
//  - negative terms: one thread per i (cheap log)
//  - compaction of nonzero-y columns: wave 0, ballot+prefix (deterministic)
//  - positive terms: one WAVE per positive i; lanes parallel over the ~51
//    compacted k entries -> single vmem round trip + shfl-max reduce.
__global__ __launch_bounds__(BLOCK) void asl_main_kernel(
    const float* __restrict__ x, const float* __restrict__ y,
    const float* __restrict__ mask, float* __restrict__ partial) {
  const int blk = blockIdx.x;
  const int b = blk & (BB - 1);       // consecutive blocks: same i-range, diff batch
  const int chunk = blk >> 7;         // blk / BB
  const int i0 = chunk * CHUNK;
  const int tid = threadIdx.x;
  const int lane = tid & 63;
  const int wid = tid >> 6;

  __shared__ unsigned short jidx[CC]; // compacted nonzero-y column indices
  __shared__ float jw[CC];            // x[b,j]^2 for those columns
  __shared__ int s_n;
  __shared__ float red[NW];

  const float* xb = x + (size_t)b * CC;
  const float* yb = y + (size_t)b * CC;

  float acc = 0.0f;

  // ---- negative terms for this i-chunk ----
  if (tid < CHUNK) {
    int i = i0 + tid;
    float yv = yb[i];
    if (yv == 0.0f) {
      float xv = xb[i];
      float x2 = xv * xv;
      acc += (x2 * x2) * logf(1.0f - xv);   // xp = x; xp^4 * log(1-xp)
    }
  }

  // ---- wave 0: compact full row's nonzero-y entries into LDS ----
  if (wid == 0) {
    const float4* x4 = (const float4*)xb;
    const float4* y4 = (const float4*)yb;
    float4 xq[4], yq[4];
    #pragma unroll
    for (int c = 0; c < 4; ++c) {
      xq[c] = x4[lane + 64 * c];
      yq[c] = y4[lane + 64 * c];
    }
    int base = 0;
    #pragma unroll
    for (int c = 0; c < 4; ++c) {
      float yv[4] = {yq[c].x, yq[c].y, yq[c].z, yq[c].w};
      float xv[4] = {xq[c].x, xq[c].y, xq[c].z, xq[c].w};
      #pragma unroll
      for (int q = 0; q < 4; ++q) {
        bool p = (yv[q] != 0.0f);
        unsigned long long bal = __ballot(p);
        int pre = __popcll(bal & ((1ull << lane) - 1ull));
        if (p) {
          int pos = base + pre;
          jidx[pos] = (unsigned short)(4 * (lane + 64 * c) + q);
          jw[pos] = xv[q] * xv[q];
        }
        base += __popcll(bal);
      }
    }
    if (lane == 0) s_n = base;
  }
  __syncthreads();
  const int n = s_n;

  // ---- positive terms: one wave per compacted entry that lies in our i-chunk ----
  for (int e = wid; e < n; e += NW) {
    int i = jidx[e];
    if (i >= i0 && i < i0 + CHUNK) {
      const float* mrow = mask + (size_t)i * CC;
      float mm = 0.0f;
      for (int k = lane; k < n; k += 64)
        mm = fmaxf(mm, mrow[jidx[k]] * jw[k]);   // mask is 0/1; diag => mm > 0
      #pragma unroll
      for (int off = 32; off > 0; off >>= 1)
        mm = fmaxf(mm, __shfl_xor(mm, off, 64));
      if (lane == 0) acc += logf(mm);            // GAMMA_POS=0 -> just log(xp)
    }
  }

  // ---- block reduction ----
  #pragma unroll
  for (int off = 32; off > 0; off >>= 1)
    acc += __shfl_down(acc, off, 64);
  if (lane == 0) red[wid] = acc;
  __syncthreads();
  if (tid == 0) {
    float s = 0.0f;
    #pragma unroll
    for (int w = 0; w < NW; ++w) s += red[w];
    partial[blk] = s;
  }
}

// Deterministic final reduction of NBLK partials -> scalar mean, negated.
__global__ __launch_bounds__(256) void asl_final_kernel(
    const float* __restrict__ partial, float* __restrict__ out) {
  const int tid = threadIdx.x;
  float v = 0.0f;
  for (int p = tid; p < NBLK; p += 256) v += partial[p];
  #pragma unroll
  for (int off = 32; off > 0; off >>= 1)
    v += __shfl_down(v, off, 64);
  __shared__ float s[4];
  if ((tid & 63) == 0) s[tid >> 6] = v;
  __syncthreads();
  if (tid == 0) out[0] = -(s[0] + s[1] + s[2] + s[3]) * (1.0f / (float)(BB * CC));
}

extern "C" void kernel_launch(void* const* d_in, const int* in_sizes, int n_in,
                              void* d_out, int out_size, void* d_ws, size_t ws_size,
                              hipStream_t stream) {
  const float* x    = (const float*)d_in[0];
  const float* y    = (const float*)d_in[1];
  const float* mask = (const float*)d_in[2];
  float* out = (float*)d_out;
  float* partial = (float*)d_ws;   // NBLK floats, fully rewritten each call

  asl_main_kernel<<<NBLK, BLOCK, 0, stream>>>(x, y, mask, partial);
  asl_final_kernel<<<1, 256, 0, stream>>>(partial, out);
}